// Round 5
// baseline (1653.711 us; speedup 1.0000x reference)
//
#include <hip/hip_runtime.h>
#include <hip/hip_cooperative_groups.h>
#include <math.h>

namespace cg = cooperative_groups;

#define LSEQ 2304
#define DM 128
#define DI 256
#define DS 16
#define RK 8
#define NCH 256
#define CLEN 9
#define EPSF 1e-5f
#define NB 256
#define NT 256

__device__ __forceinline__ float silu_f(float s) { return s / (1.f + __expf(-s)); }
__device__ __forceinline__ float softplus_f(float x) { return (x > 20.f) ? x : log1pf(__expf(x)); }

// One persistent cooperative kernel: 256 blocks (1/CU), 256 threads.
// Block b owns chunk b (rows 9b..9b+8) for phases X and Z; thread = channel d.
__global__ __launch_bounds__(NT, 1)
void k_mamba(const float* __restrict__ x0, const float* __restrict__ W_in_g,
             const float* __restrict__ cw_g, const float* __restrict__ cb_g,
             const float* __restrict__ Wx_g, const float* __restrict__ Wdt_g,
             const float* __restrict__ bdt_g, const float* __restrict__ Alog_g,
             const float* __restrict__ Dp_g, const float* __restrict__ Wo_g,
             const float* __restrict__ rmsw_g, float* __restrict__ out,
             float* __restrict__ seq, float* __restrict__ Pb,
             float* __restrict__ Sb) {
    cg::grid_group grid = cg::this_grid();

    __shared__ float xcs[CLEN * 260];   // xc per (row, d)
    __shared__ float dtrs[CLEN * 8];    // dt_r per (row, q)
    __shared__ float dbls[CLEN * 32];   // B|C per (row, s)
    __shared__ float Ys[CLEN * 260];    // gated y per (row, d)
    __shared__ float Os[CLEN * 129];    // out-proj per (row, c)
    __shared__ float red[CLEN * 32];
    __shared__ float scaleS[CLEN];

    const int tid = threadIdx.x;
    const int c = blockIdx.x;     // chunk id 0..255
    const int l0 = c * CLEN;
    const int d = tid;            // channel 0..255

    // ---- preload: seq[l][c] = x0[c][l] (one-time transpose) ----
    {
        const int gid = c * NT + tid;
        for (int idx = gid; idx < LSEQ * DM; idx += NB * NT) {
            const int cc = idx / LSEQ, l = idx - cc * LSEQ;
            seq[l * DM + cc] = x0[idx];   // coalesced read, scattered store
        }
    }
    grid.sync();

    for (int layer = 0; layer < 8; ++layer) {
        const float* Wi   = W_in_g + (size_t)layer * DM * 512;
        const float* cw   = cw_g   + (size_t)layer * DI * 4;
        const float* cb   = cb_g   + (size_t)layer * DI;
        const float* Wx   = Wx_g   + (size_t)layer * DI * 40;
        const float* Wdt  = Wdt_g  + (size_t)layer * RK * DI;
        const float* bdt  = bdt_g  + (size_t)layer * DI;
        const float* Alog = Alog_g + (size_t)layer * DI * DS;
        const float* Dp   = Dp_g   + (size_t)layer * DI;
        const float* Wo   = Wo_g   + (size_t)layer * DI * DM;
        const float* rmsw = rmsw_g + (size_t)layer * DM;

        // ================= Phase X =================
        // gemm_in: thread d computes x-col d for rows l0-3..l0+8 (12, incl
        // conv halo) and z-col d for rows l0..l0+8. seq reads are
        // wave-uniform (scalar-load path); W reads coalesced.
        float ax[12], az[9];
#pragma unroll
        for (int r = 0; r < 12; ++r) ax[r] = 0.f;
#pragma unroll
        for (int r = 0; r < 9; ++r) az[r] = 0.f;
        if (c == 0) {
#pragma unroll 4
            for (int k = 0; k < DM; ++k) {
                const float bx = Wi[k * 512 + d];
                const float bz = Wi[k * 512 + 256 + d];
#pragma unroll
                for (int r = 3; r < 12; ++r) {
                    const float a = seq[(l0 + r - 3) * DM + k];
                    ax[r] += a * bx;
                    az[r - 3] += a * bz;
                }
            }
        } else {
#pragma unroll 4
            for (int k = 0; k < DM; ++k) {
                const float bx = Wi[k * 512 + d];
                const float bz = Wi[k * 512 + 256 + d];
#pragma unroll
                for (int r = 0; r < 12; ++r) {
                    const float a = seq[(l0 + r - 3) * DM + k];
                    ax[r] += a * bx;
                    if (r >= 3) az[r - 3] += a * bz;
                }
            }
        }

        // conv4 + silu (from own registers; halo rows are ax[0..2]) + gate z
        float sz[9], xcv[9];
        {
            const float w0 = cw[d * 4 + 0], w1 = cw[d * 4 + 1];
            const float w2 = cw[d * 4 + 2], w3 = cw[d * 4 + 3];
            const float cbv = cb[d];
#pragma unroll
            for (int r = 0; r < 9; ++r) {
                sz[r] = silu_f(az[r]);
                const float v = silu_f(cbv + w0 * ax[r] + w1 * ax[r + 1] +
                                       w2 * ax[r + 2] + w3 * ax[r + 3]);
                xcv[r] = v;
                xcs[r * 260 + d] = v;
            }
        }
        __syncthreads();

        // xproj: 9 rows x 40 outputs, K=256 (xcs broadcast reads, Wx in L2)
        for (int idx = tid; idx < CLEN * 40; idx += NT) {
            const int r = idx / 40, j = idx - r * 40;
            const float* xr = &xcs[r * 260];
            float acc = 0.f;
#pragma unroll 4
            for (int k = 0; k < DI; ++k) acc += xr[k] * Wx[k * 40 + j];
            if (j < RK) dtrs[r * 8 + j] = acc;
            else dbls[r * 32 + (j - 8)] = acc;
        }
        __syncthreads();

        // dt = softplus(dt_r @ Wdt + bdt)
        float dtv[9];
        {
            float wdt[8];
#pragma unroll
            for (int q = 0; q < 8; ++q) wdt[q] = Wdt[q * DI + d];
            const float bdv = bdt[d];
#pragma unroll
            for (int r = 0; r < 9; ++r) {
                float acc = bdv;
#pragma unroll
                for (int q = 0; q < 8; ++q) acc += dtrs[r * 8 + q] * wdt[q];
                dtv[r] = softplus_f(acc);
            }
        }

        // chunk-local scan -> P, S (thread d holds all 16 states)
        float A[16];
        {
#pragma unroll
            for (int v = 0; v < 4; ++v) {
                const float4 a4 = *(const float4*)&Alog[d * DS + v * 4];
                A[v * 4 + 0] = -__expf(a4.x);
                A[v * 4 + 1] = -__expf(a4.y);
                A[v * 4 + 2] = -__expf(a4.z);
                A[v * 4 + 3] = -__expf(a4.w);
            }
            float pr[16], hs[16];
#pragma unroll
            for (int s = 0; s < 16; ++s) { pr[s] = 1.f; hs[s] = 0.f; }
            for (int t = 0; t < CLEN; ++t) {
                const float dtt = dtv[t];
                const float uv = dtt * xcv[t];
#pragma unroll
                for (int s = 0; s < 16; ++s) {
                    const float e = __expf(dtt * A[s]);
                    pr[s] *= e;
                    hs[s] = e * hs[s] + uv * dbls[t * 32 + s];
                }
            }
            const int base = c * (DI * DS) + d * DS;
#pragma unroll
            for (int v = 0; v < 4; ++v) {
                *(float4*)&Pb[base + v * 4] =
                    make_float4(pr[v * 4], pr[v * 4 + 1], pr[v * 4 + 2], pr[v * 4 + 3]);
                *(float4*)&Sb[base + v * 4] =
                    make_float4(hs[v * 4], hs[v * 4 + 1], hs[v * 4 + 2], hs[v * 4 + 3]);
            }
        }
        grid.sync();

        // ================= Phase Y: carry (blocks 0..15) =================
        {
            const int gid = c * NT + tid;
            if (gid < DI * DS) {
                float h = 0.f;
#pragma unroll 4
                for (int c2 = 0; c2 < NCH; ++c2) {
                    const int idx = c2 * (DI * DS) + gid;
                    const float p = Pb[idx];
                    const float s = Sb[idx];
                    Sb[idx] = h;        // carry INTO chunk c2
                    h = p * h + s;
                }
            }
        }
        grid.sync();

        // ================= Phase Z =================
        // re-scan with carry (dt/xc/B/C/sz still live in regs/LDS), gate -> Ys
        {
            float h[16];
#pragma unroll
            for (int v = 0; v < 4; ++v) {
                const float4 h4 = *(const float4*)&Sb[c * (DI * DS) + d * DS + v * 4];
                h[v * 4 + 0] = h4.x; h[v * 4 + 1] = h4.y;
                h[v * 4 + 2] = h4.z; h[v * 4 + 3] = h4.w;
            }
            const float dskip = Dp[d];
#pragma unroll
            for (int t = 0; t < CLEN; ++t) {
                const float dtt = dtv[t];
                const float uv = dtt * xcv[t];
                float sum = 0.f;
#pragma unroll
                for (int s = 0; s < 16; ++s) {
                    const float e = __expf(dtt * A[s]);
                    h[s] = e * h[s] + uv * dbls[t * 32 + s];
                    sum += h[s] * dbls[t * 32 + 16 + s];
                }
                Ys[t * 260 + d] = (sum + dskip * xcv[t]) * sz[t];
            }
        }
        __syncthreads();

        // out-GEMM: 9x128, K=256 split in two halves across rowgroups
        {
            const int cc = tid & 127;
            const int kg = tid >> 7;
            const int k0 = kg * 128;
            float acc[9];
#pragma unroll
            for (int r = 0; r < 9; ++r) acc[r] = 0.f;
#pragma unroll 2
            for (int k = k0; k < k0 + 128; ++k) {
                const float w = Wo[k * DM + cc];
#pragma unroll
                for (int r = 0; r < 9; ++r) acc[r] += Ys[r * 260 + k] * w;
            }
            if (kg == 0) {
#pragma unroll
                for (int r = 0; r < 9; ++r) Os[r * 129 + cc] = acc[r];
            }
            __syncthreads();
            if (kg == 1) {
#pragma unroll
                for (int r = 0; r < 9; ++r) Os[r * 129 + cc] += acc[r];
            }
            __syncthreads();
        }

        // rmsnorm + store (transposed to d_out on last layer)
        for (int idx = tid; idx < CLEN * 32; idx += NT) {
            const int r = idx >> 5, part = idx & 31;
            float ss = 0.f;
#pragma unroll
            for (int i = 0; i < 4; ++i) {
                const float v = Os[r * 129 + part * 4 + i];
                ss += v * v;
            }
            red[idx] = ss;
        }
        __syncthreads();
        if (tid < CLEN) {
            float ss = 0.f;
#pragma unroll
            for (int p = 0; p < 32; ++p) ss += red[tid * 32 + p];
            scaleS[tid] = rsqrtf(ss * (1.f / DM) + EPSF);
        }
        __syncthreads();
        if (layer == 7) {
            for (int idx = tid; idx < CLEN * DM; idx += NT) {
                const int r = idx >> 7, cc = idx & 127;
                out[cc * LSEQ + (l0 + r)] = Os[r * 129 + cc] * scaleS[r] * rmsw[cc];
            }
        } else {
            for (int idx = tid; idx < CLEN * DM; idx += NT) {
                const int r = idx >> 7, cc = idx & 127;
                seq[(l0 + r) * DM + cc] = Os[r * 129 + cc] * scaleS[r] * rmsw[cc];
            }
        }
        grid.sync();   // seq visible to next layer's halo reads
    }
}

// ---------------------------------------------------------------------------
extern "C" void kernel_launch(void* const* d_in, const int* in_sizes, int n_in,
                              void* d_out, int out_size, void* d_ws, size_t ws_size,
                              hipStream_t stream) {
    const float* x    = (const float*)d_in[0];
    const float* W_in = (const float*)d_in[1];
    const float* cw   = (const float*)d_in[2];
    const float* cb   = (const float*)d_in[3];
    const float* Wx   = (const float*)d_in[4];
    const float* Wdt  = (const float*)d_in[5];
    const float* bdt  = (const float*)d_in[6];
    const float* Alog = (const float*)d_in[7];
    const float* Dp   = (const float*)d_in[8];
    const float* Wo   = (const float*)d_in[9];
    const float* rmsw = (const float*)d_in[10];
    float* out = (float*)d_out;

    float* ws  = (float*)d_ws;
    float* seq = ws; ws += LSEQ * DM;        // 294912
    float* Pb  = ws; ws += NCH * DI * DS;    // 1048576
    float* Sb  = ws; ws += NCH * DI * DS;    // 1048576

    void* args[] = { (void*)&x, (void*)&W_in, (void*)&cw, (void*)&cb,
                     (void*)&Wx, (void*)&Wdt, (void*)&bdt, (void*)&Alog,
                     (void*)&Dp, (void*)&Wo, (void*)&rmsw, (void*)&out,
                     (void*)&seq, (void*)&Pb, (void*)&Sb };
    hipLaunchCooperativeKernel((const void*)k_mamba, dim3(NB), dim3(NT),
                               args, 0, stream);
}

// Round 6
// 1039.457 us; speedup vs baseline: 1.5909x; 1.5909x over previous
//
#include <hip/hip_runtime.h>
#include <math.h>

#define LSEQ 2304
#define DM 128
#define DI 256
#define DS 16
#define RK 8
#define NCH 288     // 8-row chunks
#define CLEN 8
#define EPSF 1e-5f

__device__ __forceinline__ float silu_f(float s) { return s / (1.f + __expf(-s)); }
__device__ __forceinline__ float softplus_f(float x) { return (x > 20.f) ? x : log1pf(__expf(x)); }

// ---------------------------------------------------------------------------
// A: [xbuf | silu(z)] = seq @ W_in   (M=2304, K=128, N=512)
// grid (144, 4): 16 rows x 128 cols per block; 256 thr = 128 cols x 2 rowgroups(8).
template<bool FIRST>
__global__ __launch_bounds__(256, 4)
void k_gemm_in(const float* __restrict__ seq, const float* __restrict__ x0,
               const float* __restrict__ W, float* __restrict__ xbuf,
               float* __restrict__ sz) {
    __shared__ float As[16 * 129];
    const int l0 = blockIdx.x * 16;
    const int cb = blockIdx.y;  // 0..3
    const int tid = threadIdx.x;
    if (FIRST) {
        for (int i = tid; i < 16 * DM; i += 256) {
            int r = i & 15, c = i >> 4;
            As[r * 129 + c] = x0[c * LSEQ + l0 + r];
        }
    } else {
        for (int i = tid; i < 16 * DM; i += 256) {
            int c = i & 127, r = i >> 7;
            As[r * 129 + c] = seq[(l0 + r) * DM + c];
        }
    }
    __syncthreads();
    const int j = tid & 127;
    const int rg = tid >> 7;  // rows rg*8 .. rg*8+7
    const int jg = cb * 128 + j;
    float acc[8];
#pragma unroll
    for (int rr = 0; rr < 8; ++rr) acc[rr] = 0.f;
    for (int k = 0; k < DM; ++k) {
        const float b = W[k * 512 + jg];
#pragma unroll
        for (int rr = 0; rr < 8; ++rr) acc[rr] += As[(rg * 8 + rr) * 129 + k] * b;
    }
    if (cb < 2) {
#pragma unroll
        for (int rr = 0; rr < 8; ++rr)
            xbuf[(l0 + rg * 8 + rr) * DI + jg] = acc[rr];
    } else {
#pragma unroll
        for (int rr = 0; rr < 8; ++rr)
            sz[(l0 + rg * 8 + rr) * DI + (jg - 256)] = silu_f(acc[rr]);
    }
}

// ---------------------------------------------------------------------------
// B: conv4+silu -> xc ; xc @ Wx -> (dtr, B, C) ; dt = softplus(dtr@Wdt+bdt);
//    chunk-local scan -> P, S.  grid 288 (8-row chunks); block 256 (thread=d).
__global__ __launch_bounds__(256, 2)
void k_mid(const float* __restrict__ xbuf,
           const float* __restrict__ cw, const float* __restrict__ cbias,
           const float* __restrict__ Wx,
           const float* __restrict__ Wdt, const float* __restrict__ bdt,
           const float* __restrict__ Alog,
           float* __restrict__ xc_g, float* __restrict__ dbl_g,
           float* __restrict__ dt_g,
           float* __restrict__ P, float* __restrict__ S) {
    __shared__ float xcs[CLEN * 256];   // [r][d]
    __shared__ float dbls[CLEN * 32];   // [r][j-8]
    __shared__ float dtrs[CLEN * 8];    // [r][q]
    const int c = blockIdx.x;
    const int l0 = c * CLEN;
    const int tid = threadIdx.x;
    const int d = tid;

    // conv + silu
    float xv[CLEN + 3];
#pragma unroll
    for (int t = 0; t < CLEN + 3; ++t) {
        const int l = l0 + t - 3;
        xv[t] = (l >= 0) ? xbuf[l * DI + d] : 0.f;
    }
    const float w0 = cw[d * 4 + 0], w1 = cw[d * 4 + 1];
    const float w2 = cw[d * 4 + 2], w3 = cw[d * 4 + 3];
    const float cbv = cbias[d];
    float xcv[CLEN];
#pragma unroll
    for (int r = 0; r < CLEN; ++r) {
        const float v = silu_f(cbv + w0 * xv[r] + w1 * xv[r + 1] +
                               w2 * xv[r + 2] + w3 * xv[r + 3]);
        xcv[r] = v;
        xcs[r * 256 + d] = v;
        xc_g[(l0 + r) * DI + d] = v;
    }
    __syncthreads();

    // xproj: CLEN*40 = 320 outputs, K=256 (LDS broadcast + L2-hot Wx)
    for (int idx = tid; idx < CLEN * 40; idx += 256) {
        const int r = idx / 40, j = idx - r * 40;
        const float* xr = &xcs[r * 256];
        float acc = 0.f;
#pragma unroll 4
        for (int k = 0; k < DI; ++k) acc += xr[k] * Wx[k * 40 + j];
        if (j < RK) dtrs[r * 8 + j] = acc;
        else {
            dbls[r * 32 + (j - 8)] = acc;
            dbl_g[(l0 + r) * 32 + (j - 8)] = acc;
        }
    }
    __syncthreads();

    // dt = softplus(dtr @ Wdt + bdt)
    float dtv[CLEN];
    {
        float wdt[8];
#pragma unroll
        for (int q = 0; q < 8; ++q) wdt[q] = Wdt[q * DI + d];
        const float bdv = bdt[d];
#pragma unroll
        for (int r = 0; r < CLEN; ++r) {
            float acc = bdv;
#pragma unroll
            for (int q = 0; q < 8; ++q) acc += dtrs[r * 8 + q] * wdt[q];
            dtv[r] = softplus_f(acc);
            dt_g[(l0 + r) * DI + d] = dtv[r];
        }
    }

    // chunk-local scan: thread d holds 16 states
    float A[16], pr[16], hs[16];
#pragma unroll
    for (int v = 0; v < 4; ++v) {
        const float4 a4 = *(const float4*)&Alog[d * DS + v * 4];
        A[v * 4 + 0] = -__expf(a4.x);
        A[v * 4 + 1] = -__expf(a4.y);
        A[v * 4 + 2] = -__expf(a4.z);
        A[v * 4 + 3] = -__expf(a4.w);
    }
#pragma unroll
    for (int s = 0; s < 16; ++s) { pr[s] = 1.f; hs[s] = 0.f; }
#pragma unroll
    for (int t = 0; t < CLEN; ++t) {
        const float dtt = dtv[t];
        const float uv = dtt * xcv[t];
        const float* Brow = &dbls[t * 32];
#pragma unroll
        for (int s = 0; s < 16; ++s) {
            const float e = __expf(dtt * A[s]);
            pr[s] *= e;
            hs[s] = e * hs[s] + uv * Brow[s];
        }
    }
    const int base = c * (DI * DS) + d * DS;
#pragma unroll
    for (int v = 0; v < 4; ++v) {
        *(float4*)&P[base + v * 4] =
            make_float4(pr[v * 4], pr[v * 4 + 1], pr[v * 4 + 2], pr[v * 4 + 3]);
        *(float4*)&S[base + v * 4] =
            make_float4(hs[v * 4], hs[v * 4 + 1], hs[v * 4 + 2], hs[v * 4 + 3]);
    }
}

// ---------------------------------------------------------------------------
// C: chunk carries in place: S[c] <- carry INTO chunk c. grid 64 x 64.
__global__ __launch_bounds__(64, 8)
void k_carry(const float* __restrict__ P, float* __restrict__ S) {
    const int i = blockIdx.x * 64 + threadIdx.x;
    float h = 0.f;
#pragma unroll 4
    for (int c = 0; c < NCH; ++c) {
        const int idx = c * (DI * DS) + i;
        const float p = P[idx];
        const float s = S[idx];
        S[idx] = h;
        h = p * h + s;
    }
}

// ---------------------------------------------------------------------------
// D: re-scan with carry + gate + out-GEMM + rmsnorm. grid 288; block 256.
template<bool LAST>
__global__ __launch_bounds__(256, 2)
void k_tail(const float* __restrict__ dt_g, const float* __restrict__ xc_g,
            const float* __restrict__ dbl_g, const float* __restrict__ Alog,
            const float* __restrict__ H, const float* __restrict__ Dp,
            const float* __restrict__ sz, const float* __restrict__ Wo,
            const float* __restrict__ rmsw, float* __restrict__ seq,
            float* __restrict__ out) {
    __shared__ float dbls[CLEN * 32];
    __shared__ float Ys[CLEN * 256];
    __shared__ float Os[CLEN * 129];
    __shared__ float red[CLEN * 32];
    __shared__ float scaleS[CLEN];
    const int c = blockIdx.x;
    const int l0 = c * CLEN;
    const int tid = threadIdx.x;
    const int d = tid;

    dbls[tid] = dbl_g[l0 * 32 + tid];  // CLEN*32 == 256

    float A[16], h[16];
#pragma unroll
    for (int v = 0; v < 4; ++v) {
        const float4 a4 = *(const float4*)&Alog[d * DS + v * 4];
        A[v * 4 + 0] = -__expf(a4.x);
        A[v * 4 + 1] = -__expf(a4.y);
        A[v * 4 + 2] = -__expf(a4.z);
        A[v * 4 + 3] = -__expf(a4.w);
        const float4 h4 = *(const float4*)&H[c * (DI * DS) + d * DS + v * 4];
        h[v * 4 + 0] = h4.x; h[v * 4 + 1] = h4.y;
        h[v * 4 + 2] = h4.z; h[v * 4 + 3] = h4.w;
    }
    float dtv[CLEN], xcv[CLEN], szv[CLEN];
#pragma unroll
    for (int r = 0; r < CLEN; ++r) {
        dtv[r] = dt_g[(l0 + r) * DI + d];
        xcv[r] = xc_g[(l0 + r) * DI + d];
        szv[r] = sz[(l0 + r) * DI + d];
    }
    const float dskip = Dp[d];
    __syncthreads();
#pragma unroll
    for (int t = 0; t < CLEN; ++t) {
        const float dtt = dtv[t];
        const float uv = dtt * xcv[t];
        float sum = 0.f;
#pragma unroll
        for (int s = 0; s < 16; ++s) {
            const float e = __expf(dtt * A[s]);
            h[s] = e * h[s] + uv * dbls[t * 32 + s];
            sum += h[s] * dbls[t * 32 + 16 + s];
        }
        Ys[t * 256 + d] = (sum + dskip * xcv[t]) * szv[t];
    }
    __syncthreads();

    // out-GEMM: CLEN x 128, K=256 split across 2 k-groups
    {
        const int cc = tid & 127;
        const int kg = tid >> 7;
        const int k0 = kg * 128;
        float acc[CLEN];
#pragma unroll
        for (int r = 0; r < CLEN; ++r) acc[r] = 0.f;
#pragma unroll 2
        for (int k = k0; k < k0 + 128; ++k) {
            const float w = Wo[k * DM + cc];
#pragma unroll
            for (int r = 0; r < CLEN; ++r) acc[r] += Ys[r * 256 + k] * w;
        }
        if (kg == 0) {
#pragma unroll
            for (int r = 0; r < CLEN; ++r) Os[r * 129 + cc] = acc[r];
        }
        __syncthreads();
        if (kg == 1) {
#pragma unroll
            for (int r = 0; r < CLEN; ++r) Os[r * 129 + cc] += acc[r];
        }
        __syncthreads();
    }

    // rmsnorm + store
    {
        const int r = tid >> 5, part = tid & 31;
        float ss = 0.f;
#pragma unroll
        for (int i = 0; i < 4; ++i) {
            const float v = Os[r * 129 + part * 4 + i];
            ss += v * v;
        }
        red[tid] = ss;
    }
    __syncthreads();
    if (tid < CLEN) {
        float ss = 0.f;
#pragma unroll
        for (int p = 0; p < 32; ++p) ss += red[tid * 32 + p];
        scaleS[tid] = rsqrtf(ss * (1.f / DM) + EPSF);
    }
    __syncthreads();
    if (LAST) {
        for (int idx = tid; idx < CLEN * DM; idx += 256) {
            const int r = idx >> 7, cc = idx & 127;
            out[cc * LSEQ + (l0 + r)] = Os[r * 129 + cc] * scaleS[r] * rmsw[cc];
        }
    } else {
        for (int idx = tid; idx < CLEN * DM; idx += 256) {
            const int r = idx >> 7, cc = idx & 127;
            seq[(l0 + r) * DM + cc] = Os[r * 129 + cc] * scaleS[r] * rmsw[cc];
        }
    }
}

// ---------------------------------------------------------------------------
extern "C" void kernel_launch(void* const* d_in, const int* in_sizes, int n_in,
                              void* d_out, int out_size, void* d_ws, size_t ws_size,
                              hipStream_t stream) {
    const float* x    = (const float*)d_in[0];
    const float* W_in = (const float*)d_in[1];
    const float* cw   = (const float*)d_in[2];
    const float* cb   = (const float*)d_in[3];
    const float* Wx   = (const float*)d_in[4];
    const float* Wdt  = (const float*)d_in[5];
    const float* bdt  = (const float*)d_in[6];
    const float* Alog = (const float*)d_in[7];
    const float* Dp   = (const float*)d_in[8];
    const float* Wo   = (const float*)d_in[9];
    const float* rmsw = (const float*)d_in[10];
    float* out = (float*)d_out;

    float* ws   = (float*)d_ws;
    float* seq  = ws; ws += LSEQ * DM;
    float* xbuf = ws; ws += LSEQ * DI;
    float* szb  = ws; ws += LSEQ * DI;
    float* xcb  = ws; ws += LSEQ * DI;
    float* dtb  = ws; ws += LSEQ * DI;
    float* dblb = ws; ws += LSEQ * 32;
    float* Pb   = ws; ws += NCH * DI * DS;
    float* Sb   = ws; ws += NCH * DI * DS;

    for (int layer = 0; layer < 8; ++layer) {
        const float* Wi_l   = W_in + (size_t)layer * DM * 512;
        const float* cw_l   = cw   + (size_t)layer * DI * 4;
        const float* cb_l   = cb   + (size_t)layer * DI;
        const float* Wx_l   = Wx   + (size_t)layer * DI * 40;
        const float* Wdt_l  = Wdt  + (size_t)layer * RK * DI;
        const float* bdt_l  = bdt  + (size_t)layer * DI;
        const float* Alog_l = Alog + (size_t)layer * DI * DS;
        const float* Dp_l   = Dp   + (size_t)layer * DI;
        const float* Wo_l   = Wo   + (size_t)layer * DI * DM;
        const float* rmsw_l = rmsw + (size_t)layer * DM;

        if (layer == 0)
            k_gemm_in<true><<<dim3(144, 4), 256, 0, stream>>>(seq, x, Wi_l, xbuf, szb);
        else
            k_gemm_in<false><<<dim3(144, 4), 256, 0, stream>>>(seq, x, Wi_l, xbuf, szb);

        k_mid<<<NCH, 256, 0, stream>>>(xbuf, cw_l, cb_l, Wx_l, Wdt_l, bdt_l, Alog_l,
                                       xcb, dblb, dtb, Pb, Sb);

        k_carry<<<64, 64, 0, stream>>>(Pb, Sb);

        if (layer == 7)
            k_tail<true><<<NCH, 256, 0, stream>>>(dtb, xcb, dblb, Alog_l, Sb, Dp_l,
                                                  szb, Wo_l, rmsw_l, seq, out);
        else
            k_tail<false><<<NCH, 256, 0, stream>>>(dtb, xcb, dblb, Alog_l, Sb, Dp_l,
                                                   szb, Wo_l, rmsw_l, seq, out);
    }
}